// Round 1
// baseline (3609.115 us; speedup 1.0000x reference)
//
#include <hip/hip_runtime.h>
#include <hip/hip_bf16.h>
#include <math.h>

constexpr int Bn = 32, Nn = 4096, Dn = 512, NSn = 16, HIn = 128;
constexpr float kScale = 0.04419417382415922f; // 512^-0.5
constexpr float kEps = 1e-8f;

__device__ __forceinline__ float wred(float v) {
#pragma unroll
  for (int m = 32; m > 0; m >>= 1) v += __shfl_xor(v, m);
  return v;
}
__device__ __forceinline__ double wredd(double v) {
#pragma unroll
  for (int m = 32; m > 0; m >>= 1) v += __shfl_xor(v, m);
  return v;
}

// ---------------- per-row LN stats of inputs ----------------
__global__ __launch_bounds__(256) void k_rowstats(const float* __restrict__ in,
                                                  float* __restrict__ mu, float* __restrict__ rsig) {
  int row = blockIdx.x * 4 + (threadIdx.x >> 6);
  int lane = threadIdx.x & 63;
  const float4* p = reinterpret_cast<const float4*>(in + (size_t)row * Dn) + lane * 2;
  float4 a = p[0], b = p[1];
  float s = a.x + a.y + a.z + a.w + b.x + b.y + b.z + b.w;
  float q = a.x*a.x + a.y*a.y + a.z*a.z + a.w*a.w + b.x*b.x + b.y*b.y + b.z*b.z + b.w*b.w;
  s = wred(s); q = wred(q);
  if (lane == 0) {
    float m = s * (1.0f / 512.0f);
    float var = q * (1.0f / 512.0f) - m * m;
    mu[row] = m;
    rsig[row] = 1.0f / sqrtf(var + 1e-5f);
  }
}

// ---------------- slots init ----------------
__global__ __launch_bounds__(256) void k_slots_init(const float* __restrict__ smu, const float* __restrict__ sls,
                                                    const float* __restrict__ noise, float* __restrict__ slots) {
  int r = blockIdx.x;
  for (int d = threadIdx.x; d < Dn; d += 256)
    slots[(size_t)r * Dn + d] = smu[d] + expf(sls[d]) * noise[(size_t)r * Dn + d];
}

// ---------------- LN of [R,512] rows ----------------
__global__ __launch_bounds__(256) void k_ln_rows(const float* __restrict__ src, const float* __restrict__ w,
                                                 const float* __restrict__ b, float* __restrict__ dst) {
  int r = blockIdx.x;
  __shared__ float red[8];
  int t = threadIdx.x;
  float x0 = src[(size_t)r * Dn + t], x1 = src[(size_t)r * Dn + 256 + t];
  float s = x0 + x1, q = x0 * x0 + x1 * x1;
  s = wred(s); q = wred(q);
  if ((t & 63) == 0) { red[t >> 6] = s; red[4 + (t >> 6)] = q; }
  __syncthreads();
  float S = red[0] + red[1] + red[2] + red[3];
  float Q = red[4] + red[5] + red[6] + red[7];
  float m = S * (1.0f / 512.0f);
  float rs = 1.0f / sqrtf(Q * (1.0f / 512.0f) - m * m + 1e-5f);
  dst[(size_t)r * Dn + t] = (x0 - m) * rs * w[t] + b[t];
  dst[(size_t)r * Dn + 256 + t] = (x1 - m) * rs * w[256 + t] + b[256 + t];
}

// ---------------- small GEMM: out = act(A@W (+bias) (+out)) ----------------
template <bool TRANS, bool RELU, bool ADD>
__global__ __launch_bounds__(256) void k_gemm_sm(const float* __restrict__ A, const float* __restrict__ W,
                                                 const float* __restrict__ bias, float* __restrict__ out,
                                                 int Nc, int K) {
  __shared__ float as_[64][17];
  __shared__ float ws_[16][65];
  int m0 = blockIdx.y * 64, n0 = blockIdx.x * 64;
  int t = threadIdx.x, tx = t & 15, ty = t >> 4;
  float acc[4][4] = {};
  for (int k0 = 0; k0 < K; k0 += 16) {
#pragma unroll
    for (int e = 0; e < 4; ++e) {
      int idx = t + e * 256;
      int r = idx >> 4, c = idx & 15;
      as_[r][c] = A[(size_t)(m0 + r) * K + k0 + c];
    }
#pragma unroll
    for (int e = 0; e < 4; ++e) {
      int idx = t + e * 256;
      if (!TRANS) {
        int r = idx >> 6, c = idx & 63;
        ws_[r][c] = W[(size_t)(k0 + r) * Nc + n0 + c];
      } else {
        int r = idx >> 4, c = idx & 15;
        ws_[c][r] = W[(size_t)(n0 + r) * K + k0 + c];
      }
    }
    __syncthreads();
#pragma unroll
    for (int kc = 0; kc < 16; ++kc) {
      float av[4], wv[4];
#pragma unroll
      for (int i = 0; i < 4; ++i) av[i] = as_[ty * 4 + i][kc];
#pragma unroll
      for (int j = 0; j < 4; ++j) wv[j] = ws_[kc][tx * 4 + j];
#pragma unroll
      for (int i = 0; i < 4; ++i)
#pragma unroll
        for (int j = 0; j < 4; ++j) acc[i][j] += av[i] * wv[j];
    }
    __syncthreads();
  }
#pragma unroll
  for (int i = 0; i < 4; ++i)
#pragma unroll
    for (int j = 0; j < 4; ++j) {
      int m = m0 + ty * 4 + i, n = n0 + tx * 4 + j;
      float v = acc[i][j] + bias[n];
      if (RELU) v = fmaxf(v, 0.0f);
      if (ADD) v += out[(size_t)m * Nc + n];
      out[(size_t)m * Nc + n] = v;
    }
}

// ---------------- u = Wk_h @ q, folded with LN weights + SCALE ----------------
__global__ __launch_bounds__(256) void k_qkt(const float* __restrict__ q, const float* __restrict__ Wk,
                                             const float* __restrict__ bk, const float* __restrict__ lnw,
                                             const float* __restrict__ lnb, float* __restrict__ qkt,
                                             float* __restrict__ alpha, float* __restrict__ beta) {
  int b = blockIdx.y, hi = blockIdx.x, h = hi >> 4, i = hi & 15;
  __shared__ __align__(16) float qs[64];
  __shared__ float r2[8];
  int t = threadIdx.x;
  if (t < 64) qs[t] = q[(size_t)(b * NSn + i) * Dn + h * 64 + t];
  __syncthreads();
  float pa = 0.0f, pb = 0.0f;
  for (int d = t; d < Dn; d += 256) {
    const float4* wr = reinterpret_cast<const float4*>(Wk + (size_t)d * Dn + h * 64);
    const float4* q4 = reinterpret_cast<const float4*>(qs);
    float u = 0.0f;
#pragma unroll
    for (int k = 0; k < 16; ++k) {
      float4 wv = wr[k], qv = q4[k];
      u += wv.x * qv.x + wv.y * qv.y + wv.z * qv.z + wv.w * qv.w;
    }
    qkt[(size_t)(b * HIn + hi) * Dn + d] = kScale * lnw[d] * u;
    pa += lnb[d] * u;
    pb += lnw[d] * u;
  }
  pa = wred(pa); pb = wred(pb);
  if ((t & 63) == 0) { r2[t >> 6] = pa; r2[4 + (t >> 6)] = pb; }
  __syncthreads();
  if (t == 0) {
    float qb_ = 0.0f;
    for (int k = 0; k < 64; ++k) qb_ += qs[k] * bk[h * 64 + k];
    alpha[b * HIn + hi] = kScale * (r2[0] + r2[1] + r2[2] + r2[3] + qb_);
    beta[b * HIn + hi]  = kScale * (r2[4] + r2[5] + r2[6] + r2[7]);
  }
}

// ---------------- dots GEMM + softmax over slots + EPS + partial sums ----------------
__global__ __launch_bounds__(256) void k_dots(const float* __restrict__ in, const float* __restrict__ qkt,
                                              const float* __restrict__ alpha, const float* __restrict__ beta,
                                              const float* __restrict__ mu, const float* __restrict__ rsig,
                                              float* __restrict__ A, float* __restrict__ Spart,
                                              float* __restrict__ c1part) {
  int b = blockIdx.y, jt = blockIdx.x, j0 = jt * 128;
  __shared__ __align__(16) float xs[16][132];
  __shared__ __align__(16) float us[16][132];
  __shared__ float sm[64][132];
  __shared__ float rsL[128], muL[128], aL[128], bL[128];
  int t = threadIdx.x, tx = t & 15, ty = t >> 4;
  float acc[8][8] = {};
  const size_t inbase = ((size_t)b * Nn + j0) * Dn;
  const size_t ubase = (size_t)b * HIn * Dn;
  for (int k0 = 0; k0 < Dn; k0 += 16) {
#pragma unroll
    for (int e = 0; e < 8; ++e) {
      int idx = t + e * 256;
      int r = idx >> 4, c = idx & 15;
      xs[c][r] = in[inbase + (size_t)r * Dn + k0 + c];
    }
#pragma unroll
    for (int e = 0; e < 8; ++e) {
      int idx = t + e * 256;
      int r = idx >> 4, c = idx & 15;
      us[c][r] = qkt[ubase + (size_t)r * Dn + k0 + c];
    }
    __syncthreads();
#pragma unroll
    for (int kc = 0; kc < 16; ++kc) {
      float4 x0 = *reinterpret_cast<const float4*>(&xs[kc][ty * 8]);
      float4 x1 = *reinterpret_cast<const float4*>(&xs[kc][ty * 8 + 4]);
      float4 u0 = *reinterpret_cast<const float4*>(&us[kc][tx * 8]);
      float4 u1 = *reinterpret_cast<const float4*>(&us[kc][tx * 8 + 4]);
      float xv[8] = {x0.x, x0.y, x0.z, x0.w, x1.x, x1.y, x1.z, x1.w};
      float uv[8] = {u0.x, u0.y, u0.z, u0.w, u1.x, u1.y, u1.z, u1.w};
#pragma unroll
      for (int a_ = 0; a_ < 8; ++a_)
#pragma unroll
        for (int b_ = 0; b_ < 8; ++b_) acc[a_][b_] += xv[a_] * uv[b_];
    }
    __syncthreads();
  }
  if (t < 128) {
    rsL[t] = rsig[(size_t)b * Nn + j0 + t];
    muL[t] = mu[(size_t)b * Nn + j0 + t];
    aL[t] = alpha[b * HIn + t];
    bL[t] = beta[b * HIn + t];
  }
  for (int half = 0; half < 2; ++half) {
    __syncthreads();
    if ((ty >> 3) == half) {
#pragma unroll
      for (int ji = 0; ji < 8; ++ji) {
        int jl = (ty & 7) * 8 + ji;
        int jg = half * 64 + jl;
        float rs = rsL[jg], mr = muL[jg] * rs;
#pragma unroll
        for (int ui = 0; ui < 8; ++ui) {
          int hi = tx * 8 + ui;
          sm[jl][hi] = acc[ji][ui] * rs + aL[hi] - mr * bL[hi];
        }
      }
    }
    __syncthreads();
    for (int task = t; task < 512; task += 256) {
      int j = task & 63, h = task >> 6;
      float* p = &sm[j][h * 16];
      float mx = p[0];
#pragma unroll
      for (int i = 1; i < 16; ++i) mx = fmaxf(mx, p[i]);
      float e[16];
      float ssum = 0.0f;
#pragma unroll
      for (int i = 0; i < 16; ++i) { e[i] = expf(p[i] - mx); ssum += e[i]; }
      float inv = 1.0f / ssum;
#pragma unroll
      for (int i = 0; i < 16; ++i) p[i] = e[i] * inv + kEps;
    }
    __syncthreads();
    if (t < 128) {
      float ss = 0.0f, cc = 0.0f;
#pragma unroll
      for (int j = 0; j < 64; ++j) {
        float a = sm[j][t];
        ss += a;
        cc += a * muL[half * 64 + j] * rsL[half * 64 + j];
      }
      int sub = (b * 64 + jt * 2 + half) * HIn + t;
      Spart[sub] = ss;
      c1part[sub] = cc;
    }
    for (int idx = t; idx < 8192; idx += 256) {
      int hi = idx >> 6, j = idx & 63;
      A[(size_t)(b * HIn + hi) * Nn + j0 + half * 64 + j] = sm[j][hi] * rsL[half * 64 + j];
    }
  }
}

// ---------------- reduce partial S / c1 ----------------
__global__ void k_reduceS(const float* __restrict__ Spart, const float* __restrict__ c1part,
                          float* __restrict__ S, float* __restrict__ c1) {
  int g = blockIdx.x * 256 + threadIdx.x;
  if (g >= Bn * HIn) return;
  int b = g >> 7, hi = g & 127;
  float s = 0.0f, c = 0.0f;
  for (int tj = 0; tj < 64; ++tj) {
    s += Spart[(b * 64 + tj) * HIn + hi];
    c += c1part[(b * 64 + tj) * HIn + hi];
  }
  S[g] = s;
  c1[g] = c;
}

// ---------------- AX = A @ X  (K-split x4) ----------------
__global__ __launch_bounds__(256) void k_ax(const float* __restrict__ Abuf, const float* __restrict__ in,
                                            float* __restrict__ AXp) {
  int d0 = blockIdx.x * 128;
  int kp = blockIdx.y;
  int b = blockIdx.z;
  __shared__ __align__(16) float as_[16][132];
  __shared__ __align__(16) float xs_[16][132];
  int t = threadIdx.x, tx = t & 15, ty = t >> 4;
  float acc[8][8] = {};
  for (int k0 = kp * 1024; k0 < kp * 1024 + 1024; k0 += 16) {
#pragma unroll
    for (int e = 0; e < 8; ++e) {
      int idx = t + e * 256;
      int r = idx >> 4, c = idx & 15;
      as_[c][r] = Abuf[(size_t)(b * HIn + r) * Nn + k0 + c];
    }
#pragma unroll
    for (int e = 0; e < 8; ++e) {
      int idx = t + e * 256;
      int kc = idx >> 7, dd = idx & 127;
      xs_[kc][dd] = in[((size_t)b * Nn + k0 + kc) * Dn + d0 + dd];
    }
    __syncthreads();
#pragma unroll
    for (int kc = 0; kc < 16; ++kc) {
      float4 a0 = *reinterpret_cast<const float4*>(&as_[kc][ty * 8]);
      float4 a1 = *reinterpret_cast<const float4*>(&as_[kc][ty * 8 + 4]);
      float4 x0 = *reinterpret_cast<const float4*>(&xs_[kc][tx * 8]);
      float4 x1 = *reinterpret_cast<const float4*>(&xs_[kc][tx * 8 + 4]);
      float av[8] = {a0.x, a0.y, a0.z, a0.w, a1.x, a1.y, a1.z, a1.w};
      float xv[8] = {x0.x, x0.y, x0.z, x0.w, x1.x, x1.y, x1.z, x1.w};
#pragma unroll
      for (int u = 0; u < 8; ++u)
#pragma unroll
        for (int v = 0; v < 8; ++v) acc[u][v] += av[u] * xv[v];
    }
    __syncthreads();
  }
#pragma unroll
  for (int u = 0; u < 8; ++u)
#pragma unroll
    for (int v = 0; v < 8; ++v)
      AXp[(((size_t)kp * Bn + b) * HIn + ty * 8 + u) * Dn + d0 + tx * 8 + v] = acc[u][v];
}

// ---------------- upd = ((w*(G-c1)/S + b) @ Wv_h) + bv ----------------
__global__ __launch_bounds__(256) void k_upd(const float* __restrict__ AXp, const float* __restrict__ S,
                                             const float* __restrict__ c1, const float* __restrict__ lnw,
                                             const float* __restrict__ lnb, const float* __restrict__ Wv,
                                             const float* __restrict__ bv, float* __restrict__ upd) {
  int b = blockIdx.y, hi = blockIdx.x, h = hi >> 4, i = hi & 15;
  __shared__ float vx[512];
  __shared__ float red[256];
  int t = threadIdx.x;
  float Sv = S[b * HIn + hi], c1v = c1[b * HIn + hi];
  float invS = 1.0f / Sv;
  for (int d = t; d < Dn; d += 256) {
    float G = 0.0f;
#pragma unroll
    for (int kp = 0; kp < 4; ++kp) G += AXp[(((size_t)kp * Bn + b) * HIn + hi) * Dn + d];
    vx[d] = lnw[d] * (G - c1v) * invS + lnb[d];
  }
  __syncthreads();
  int cc = t & 63, qd = t >> 6;
  float p = 0.0f;
  for (int d = qd * 128; d < qd * 128 + 128; ++d) p += vx[d] * Wv[(size_t)d * Dn + h * 64 + cc];
  red[t] = p;
  __syncthreads();
  if (qd == 0) {
    float v = red[cc] + red[64 + cc] + red[128 + cc] + red[192 + cc] + bv[h * 64 + cc];
    upd[(size_t)(b * NSn + i) * Dn + h * 64 + cc] = v;
  }
}

// ---------------- GRU (in-place slots) ----------------
__global__ __launch_bounds__(256) void k_gru(const float* __restrict__ gi, const float* __restrict__ gh,
                                             float* __restrict__ slots) {
  int r = blockIdx.x;
  for (int c = threadIdx.x; c < Dn; c += 256) {
    float xr = gi[(size_t)r * 1536 + c] + gh[(size_t)r * 1536 + c];
    float xz = gi[(size_t)r * 1536 + 512 + c] + gh[(size_t)r * 1536 + 512 + c];
    float xin = gi[(size_t)r * 1536 + 1024 + c];
    float xhn = gh[(size_t)r * 1536 + 1024 + c];
    float rg = 1.0f / (1.0f + expf(-xr));
    float zg = 1.0f / (1.0f + expf(-xz));
    float ng = tanhf(xin + rg * xhn);
    float sp = slots[(size_t)r * Dn + c];
    slots[(size_t)r * Dn + c] = (1.0f - zg) * ng + zg * sp;
  }
}

// ---------------- keep gate (zero dropped slots in place) ----------------
__global__ void k_keepscale(const float* __restrict__ Wkeep, const float* __restrict__ gk,
                            float* __restrict__ slots) {
  int g = blockIdx.x;
  int lane = threadIdx.x;
  float4* sp = reinterpret_cast<float4*>(slots + (size_t)g * Dn) + lane * 2;
  float4 s0 = sp[0], s1 = sp[1];
  float sv[8] = {s0.x, s0.y, s0.z, s0.w, s1.x, s1.y, s1.z, s1.w};
  double d0 = 0.0, d1 = 0.0;
#pragma unroll
  for (int e = 0; e < 8; ++e) {
    int d = lane * 8 + e;
    d0 += (double)sv[e] * (double)Wkeep[d * 2];
    d1 += (double)sv[e] * (double)Wkeep[d * 2 + 1];
  }
  d0 = wredd(d0);
  d1 = wredd(d1);
  int keepi = 0;
  if (lane == 0) keepi = ((d1 + (double)gk[g * 2 + 1]) > (d0 + (double)gk[g * 2])) ? 1 : 0;
  keepi = __shfl(keepi, 0);
  if (!keepi) {
    float4 z = {0.0f, 0.0f, 0.0f, 0.0f};
    sp[0] = z;
    sp[1] = z;
  }
}

// ---------------- per-slot scalars for route decomposition ----------------
__global__ void k_slotscalars(const float* __restrict__ slots, const float* __restrict__ lnw,
                              const float* __restrict__ lnb, double* __restrict__ swd,
                              double* __restrict__ sbd) {
  int g = blockIdx.x, lane = threadIdx.x;
  const float4* sp = reinterpret_cast<const float4*>(slots + (size_t)g * Dn) + lane * 2;
  const float4* wp = reinterpret_cast<const float4*>(lnw) + lane * 2;
  const float4* bp = reinterpret_cast<const float4*>(lnb) + lane * 2;
  float4 s0 = sp[0], s1 = sp[1], w0 = wp[0], w1 = wp[1], b0 = bp[0], b1 = bp[1];
  double pw = (double)s0.x * w0.x + (double)s0.y * w0.y + (double)s0.z * w0.z + (double)s0.w * w0.w +
              (double)s1.x * w1.x + (double)s1.y * w1.y + (double)s1.z * w1.z + (double)s1.w * w1.w;
  double pb = (double)s0.x * b0.x + (double)s0.y * b0.y + (double)s0.z * b0.z + (double)s0.w * b0.w +
              (double)s1.x * b1.x + (double)s1.y * b1.y + (double)s1.z * b1.z + (double)s1.w * b1.w;
  pw = wredd(pw);
  pb = wredd(pb);
  if (lane == 0) { swd[g] = pw; sbd[g] = pb; }
}

// ---------------- hard route + gather output ----------------
__global__ __launch_bounds__(256) void k_route_out(const float* __restrict__ in, const float* __restrict__ slots,
                                                   const float* __restrict__ lnw, const double* __restrict__ swd,
                                                   const double* __restrict__ sbd, const float* __restrict__ mu,
                                                   const float* __restrict__ rsig,
                                                   const float* __restrict__ g_route, float* __restrict__ out) {
  int b = blockIdx.y;
  int wav = blockIdx.x * 4 + (threadIdx.x >> 6);
  int lane = threadIdx.x & 63;
  float wv8[8];
  {
    const float4* wp = reinterpret_cast<const float4*>(lnw + lane * 8);
    float4 wa = wp[0], wb = wp[1];
    wv8[0] = wa.x; wv8[1] = wa.y; wv8[2] = wa.z; wv8[3] = wa.w;
    wv8[4] = wb.x; wv8[5] = wb.y; wv8[6] = wb.z; wv8[7] = wb.w;
  }
  float st[16][8];
#pragma unroll
  for (int i = 0; i < 16; ++i) {
    const float4* sp = reinterpret_cast<const float4*>(slots + (size_t)(b * NSn + i) * Dn + lane * 8);
    float4 sa = sp[0], sc = sp[1];
    st[i][0] = sa.x * wv8[0]; st[i][1] = sa.y * wv8[1]; st[i][2] = sa.z * wv8[2]; st[i][3] = sa.w * wv8[3];
    st[i][4] = sc.x * wv8[4]; st[i][5] = sc.y * wv8[5]; st[i][6] = sc.z * wv8[6]; st[i][7] = sc.w * wv8[7];
  }
  double sbv = 0.0, swv = 0.0;
  if (lane < 16) { sbv = sbd[b * NSn + lane]; swv = swd[b * NSn + lane]; }
  for (int j = wav; j < Nn; j += 128) {
    const float4* xp = reinterpret_cast<const float4*>(in + ((size_t)b * Nn + j) * Dn + lane * 8);
    float4 xa = xp[0], xb = xp[1];
    float xv[8] = {xa.x, xa.y, xa.z, xa.w, xb.x, xb.y, xb.z, xb.w};
    double dp[16];
#pragma unroll
    for (int i = 0; i < 16; ++i) {
      double a = 0.0;
#pragma unroll
      for (int e = 0; e < 8; ++e) a += (double)xv[e] * (double)st[i][e];
      dp[i] = a;
    }
#pragma unroll
    for (int i = 0; i < 16; ++i) {
#pragma unroll
      for (int m = 32; m > 0; m >>= 1) dp[i] += __shfl_xor(dp[i], m);
    }
    double muj = (double)mu[(size_t)b * Nn + j];
    double rsj = (double)rsig[(size_t)b * Nn + j];
    double gv = 0.0;
    if (lane < 16) gv = (double)g_route[(size_t)(b * NSn + lane) * Nn + j];
    int best = 0;
    double bestv = -1e300;
#pragma unroll
    for (int i = 0; i < 16; ++i) {
      double logit = (double)kScale * (rsj * dp[i] + __shfl(sbv, i) - muj * rsj * __shfl(swv, i)) + __shfl(gv, i);
      if (logit > bestv) { bestv = logit; best = i; }
    }
    const float4* rp = reinterpret_cast<const float4*>(slots + (size_t)(b * NSn + best) * Dn + lane * 8);
    float4 o0 = rp[0], o1 = rp[1];
    float4* op = reinterpret_cast<float4*>(out + ((size_t)b * Nn + j) * Dn + lane * 8);
    op[0] = o0;
    op[1] = o1;
  }
}

extern "C" void kernel_launch(void* const* d_in, const int* in_sizes, int n_in,
                              void* d_out, int out_size, void* d_ws, size_t ws_size,
                              hipStream_t stream) {
  (void)in_sizes; (void)n_in; (void)out_size; (void)ws_size;
  const float* in = (const float*)d_in[0];
  const float* slots_mu = (const float*)d_in[1];
  const float* slots_ls = (const float*)d_in[2];
  const float* ln_in_w = (const float*)d_in[3];
  const float* ln_in_b = (const float*)d_in[4];
  const float* ln_s_w = (const float*)d_in[5];
  const float* ln_s_b = (const float*)d_in[6];
  const float* ln_ff_w = (const float*)d_in[7];
  const float* ln_ff_b = (const float*)d_in[8];
  const float* Wq = (const float*)d_in[9];
  const float* bq = (const float*)d_in[10];
  const float* Wk = (const float*)d_in[11];
  const float* bk = (const float*)d_in[12];
  const float* Wv = (const float*)d_in[13];
  const float* bv = (const float*)d_in[14];
  const float* Wc = (const float*)d_in[15];
  const float* bc = (const float*)d_in[16];
  const float* Wih = (const float*)d_in[17];
  const float* bih = (const float*)d_in[18];
  const float* Whh = (const float*)d_in[19];
  const float* bhh = (const float*)d_in[20];
  const float* W1 = (const float*)d_in[21];
  const float* b1 = (const float*)d_in[22];
  const float* W2 = (const float*)d_in[23];
  const float* b2 = (const float*)d_in[24];
  const float* Wkeep = (const float*)d_in[25];
  const float* noise = (const float*)d_in[26];
  const float* g_keep = (const float*)d_in[27];
  const float* g_route = (const float*)d_in[28];
  float* out = (float*)d_out;

  char* wptr = (char*)d_ws;
  auto alloc = [&](size_t bytes) {
    char* p = wptr;
    wptr += (bytes + 255) & ~(size_t)255;
    return p;
  };
  float* mu = (float*)alloc((size_t)Bn * Nn * 4);
  float* rsig = (float*)alloc((size_t)Bn * Nn * 4);
  float* slots = (float*)alloc((size_t)Bn * NSn * Dn * 4);
  float* sln = (float*)alloc((size_t)Bn * NSn * Dn * 4);
  float* qbuf = (float*)alloc((size_t)Bn * NSn * Dn * 4);
  float* qkt = (float*)alloc((size_t)Bn * HIn * Dn * 4);
  float* alpha = (float*)alloc((size_t)Bn * HIn * 4);
  float* beta = (float*)alloc((size_t)Bn * HIn * 4);
  float* Abuf = (float*)alloc((size_t)Bn * HIn * Nn * 4);
  float* Spart = (float*)alloc((size_t)Bn * 64 * HIn * 4);
  float* c1part = (float*)alloc((size_t)Bn * 64 * HIn * 4);
  float* Sfull = (float*)alloc((size_t)Bn * HIn * 4);
  float* c1full = (float*)alloc((size_t)Bn * HIn * 4);
  float* AXp = (float*)alloc((size_t)4 * Bn * HIn * Dn * 4);
  float* updb = (float*)alloc((size_t)Bn * NSn * Dn * 4);
  float* updc = (float*)alloc((size_t)Bn * NSn * Dn * 4);
  float* gibuf = (float*)alloc((size_t)Bn * NSn * 1536 * 4);
  float* ghbuf = (float*)alloc((size_t)Bn * NSn * 1536 * 4);
  float* hbuf = (float*)alloc((size_t)Bn * NSn * 2048 * 4);
  double* swd = (double*)alloc((size_t)Bn * NSn * 8);
  double* sbd = (double*)alloc((size_t)Bn * NSn * 8);

  k_rowstats<<<Bn * Nn / 4, 256, 0, stream>>>(in, mu, rsig);
  k_slots_init<<<Bn * NSn, 256, 0, stream>>>(slots_mu, slots_ls, noise, slots);

  for (int it = 0; it < 3; ++it) {
    k_ln_rows<<<Bn * NSn, 256, 0, stream>>>(slots, ln_s_w, ln_s_b, sln);
    k_gemm_sm<false, false, false><<<dim3(8, 8), 256, 0, stream>>>(sln, Wq, bq, qbuf, 512, 512);
    k_qkt<<<dim3(HIn, Bn), 256, 0, stream>>>(qbuf, Wk, bk, ln_in_w, ln_in_b, qkt, alpha, beta);
    k_dots<<<dim3(Nn / 128, Bn), 256, 0, stream>>>(in, qkt, alpha, beta, mu, rsig, Abuf, Spart, c1part);
    k_reduceS<<<(Bn * HIn + 255) / 256, 256, 0, stream>>>(Spart, c1part, Sfull, c1full);
    k_ax<<<dim3(4, 4, Bn), 256, 0, stream>>>(Abuf, in, AXp);
    k_upd<<<dim3(HIn, Bn), 256, 0, stream>>>(AXp, Sfull, c1full, ln_in_w, ln_in_b, Wv, bv, updb);
    k_gemm_sm<false, false, false><<<dim3(8, 8), 256, 0, stream>>>(updb, Wc, bc, updc, 512, 512);
    k_gemm_sm<true, false, false><<<dim3(24, 8), 256, 0, stream>>>(updc, Wih, bih, gibuf, 1536, 512);
    k_gemm_sm<true, false, false><<<dim3(24, 8), 256, 0, stream>>>(slots, Whh, bhh, ghbuf, 1536, 512);
    k_gru<<<Bn * NSn, 256, 0, stream>>>(gibuf, ghbuf, slots);
    k_ln_rows<<<Bn * NSn, 256, 0, stream>>>(slots, ln_ff_w, ln_ff_b, sln);
    k_gemm_sm<false, true, false><<<dim3(32, 8), 256, 0, stream>>>(sln, W1, b1, hbuf, 2048, 512);
    k_gemm_sm<false, false, true><<<dim3(8, 8), 256, 0, stream>>>(hbuf, W2, b2, slots, 512, 2048);
  }

  k_keepscale<<<Bn * NSn, 64, 0, stream>>>(Wkeep, g_keep, slots);
  k_slotscalars<<<Bn * NSn, 64, 0, stream>>>(slots, ln_in_w, ln_in_b, swd, sbd);
  k_route_out<<<dim3(32, Bn), 256, 0, stream>>>(in, slots, ln_in_w, swd, sbd, mu, rsig, g_route, out);
}

// Round 2
// 3095.498 us; speedup vs baseline: 1.1659x; 1.1659x over previous
//
#include <hip/hip_runtime.h>
#include <hip/hip_bf16.h>
#include <math.h>

constexpr int Bn = 32, Nn = 4096, Dn = 512, NSn = 16, HIn = 128;
constexpr float kScale = 0.04419417382415922f; // 512^-0.5
constexpr float kEps = 1e-8f;

__device__ __forceinline__ float wred(float v) {
#pragma unroll
  for (int m = 32; m > 0; m >>= 1) v += __shfl_xor(v, m);
  return v;
}
__device__ __forceinline__ double wredd(double v) {
#pragma unroll
  for (int m = 32; m > 0; m >>= 1) v += __shfl_xor(v, m);
  return v;
}

// ---------------- per-row LN stats of inputs ----------------
__global__ __launch_bounds__(256) void k_rowstats(const float* __restrict__ in,
                                                  float* __restrict__ mu, float* __restrict__ rsig) {
  int row = blockIdx.x * 4 + (threadIdx.x >> 6);
  int lane = threadIdx.x & 63;
  const float4* p = reinterpret_cast<const float4*>(in + (size_t)row * Dn) + lane * 2;
  float4 a = p[0], b = p[1];
  float s = a.x + a.y + a.z + a.w + b.x + b.y + b.z + b.w;
  float q = a.x*a.x + a.y*a.y + a.z*a.z + a.w*a.w + b.x*b.x + b.y*b.y + b.z*b.z + b.w*b.w;
  s = wred(s); q = wred(q);
  if (lane == 0) {
    float m = s * (1.0f / 512.0f);
    float var = q * (1.0f / 512.0f) - m * m;
    mu[row] = m;
    rsig[row] = 1.0f / sqrtf(var + 1e-5f);
  }
}

// ---------------- slots init ----------------
__global__ __launch_bounds__(256) void k_slots_init(const float* __restrict__ smu, const float* __restrict__ sls,
                                                    const float* __restrict__ noise, float* __restrict__ slots) {
  int r = blockIdx.x;
  for (int d = threadIdx.x; d < Dn; d += 256)
    slots[(size_t)r * Dn + d] = smu[d] + expf(sls[d]) * noise[(size_t)r * Dn + d];
}

// ---------------- LN of [R,512] rows ----------------
__global__ __launch_bounds__(256) void k_ln_rows(const float* __restrict__ src, const float* __restrict__ w,
                                                 const float* __restrict__ b, float* __restrict__ dst) {
  int r = blockIdx.x;
  __shared__ float red[8];
  int t = threadIdx.x;
  float x0 = src[(size_t)r * Dn + t], x1 = src[(size_t)r * Dn + 256 + t];
  float s = x0 + x1, q = x0 * x0 + x1 * x1;
  s = wred(s); q = wred(q);
  if ((t & 63) == 0) { red[t >> 6] = s; red[4 + (t >> 6)] = q; }
  __syncthreads();
  float S = red[0] + red[1] + red[2] + red[3];
  float Q = red[4] + red[5] + red[6] + red[7];
  float m = S * (1.0f / 512.0f);
  float rs = 1.0f / sqrtf(Q * (1.0f / 512.0f) - m * m + 1e-5f);
  dst[(size_t)r * Dn + t] = (x0 - m) * rs * w[t] + b[t];
  dst[(size_t)r * Dn + 256 + t] = (x1 - m) * rs * w[256 + t] + b[256 + t];
}

// ---------------- small GEMM: out = act(A@W (+bias) (+out)) ----------------
template <bool TRANS, bool RELU, bool ADD>
__global__ __launch_bounds__(256) void k_gemm_sm(const float* __restrict__ A, const float* __restrict__ W,
                                                 const float* __restrict__ bias, float* __restrict__ out,
                                                 int Nc, int K) {
  __shared__ float as_[64][17];
  __shared__ float ws_[16][65];
  int m0 = blockIdx.y * 64, n0 = blockIdx.x * 64;
  int t = threadIdx.x, tx = t & 15, ty = t >> 4;
  float acc[4][4] = {};
  for (int k0 = 0; k0 < K; k0 += 16) {
#pragma unroll
    for (int e = 0; e < 4; ++e) {
      int idx = t + e * 256;
      int r = idx >> 4, c = idx & 15;
      as_[r][c] = A[(size_t)(m0 + r) * K + k0 + c];
    }
#pragma unroll
    for (int e = 0; e < 4; ++e) {
      int idx = t + e * 256;
      if (!TRANS) {
        int r = idx >> 6, c = idx & 63;
        ws_[r][c] = W[(size_t)(k0 + r) * Nc + n0 + c];
      } else {
        int r = idx >> 4, c = idx & 15;
        ws_[c][r] = W[(size_t)(n0 + r) * K + k0 + c];
      }
    }
    __syncthreads();
#pragma unroll
    for (int kc = 0; kc < 16; ++kc) {
      float av[4], wv[4];
#pragma unroll
      for (int i = 0; i < 4; ++i) av[i] = as_[ty * 4 + i][kc];
#pragma unroll
      for (int j = 0; j < 4; ++j) wv[j] = ws_[kc][tx * 4 + j];
#pragma unroll
      for (int i = 0; i < 4; ++i)
#pragma unroll
        for (int j = 0; j < 4; ++j) acc[i][j] += av[i] * wv[j];
    }
    __syncthreads();
  }
#pragma unroll
  for (int i = 0; i < 4; ++i)
#pragma unroll
    for (int j = 0; j < 4; ++j) {
      int m = m0 + ty * 4 + i, n = n0 + tx * 4 + j;
      float v = acc[i][j] + bias[n];
      if (RELU) v = fmaxf(v, 0.0f);
      if (ADD) v += out[(size_t)m * Nc + n];
      out[(size_t)m * Nc + n] = v;
    }
}

// ---------------- u = Wk_h @ q, folded with LN weights + SCALE ----------------
__global__ __launch_bounds__(256) void k_qkt(const float* __restrict__ q, const float* __restrict__ Wk,
                                             const float* __restrict__ bk, const float* __restrict__ lnw,
                                             const float* __restrict__ lnb, float* __restrict__ qkt,
                                             float* __restrict__ alpha, float* __restrict__ beta) {
  int b = blockIdx.y, hi = blockIdx.x, h = hi >> 4, i = hi & 15;
  __shared__ __align__(16) float qs[64];
  __shared__ float r2[8];
  int t = threadIdx.x;
  if (t < 64) qs[t] = q[(size_t)(b * NSn + i) * Dn + h * 64 + t];
  __syncthreads();
  float pa = 0.0f, pb = 0.0f;
  for (int d = t; d < Dn; d += 256) {
    const float4* wr = reinterpret_cast<const float4*>(Wk + (size_t)d * Dn + h * 64);
    const float4* q4 = reinterpret_cast<const float4*>(qs);
    float u = 0.0f;
#pragma unroll
    for (int k = 0; k < 16; ++k) {
      float4 wv = wr[k], qv = q4[k];
      u += wv.x * qv.x + wv.y * qv.y + wv.z * qv.z + wv.w * qv.w;
    }
    qkt[(size_t)(b * HIn + hi) * Dn + d] = kScale * lnw[d] * u;
    pa += lnb[d] * u;
    pb += lnw[d] * u;
  }
  pa = wred(pa); pb = wred(pb);
  if ((t & 63) == 0) { r2[t >> 6] = pa; r2[4 + (t >> 6)] = pb; }
  __syncthreads();
  if (t == 0) {
    float qb_ = 0.0f;
    for (int k = 0; k < 64; ++k) qb_ += qs[k] * bk[h * 64 + k];
    alpha[b * HIn + hi] = kScale * (r2[0] + r2[1] + r2[2] + r2[3] + qb_);
    beta[b * HIn + hi]  = kScale * (r2[4] + r2[5] + r2[6] + r2[7]);
  }
}

// ---------------- dots GEMM + softmax over slots + EPS + partial sums ----------------
__global__ __launch_bounds__(256) void k_dots(const float* __restrict__ in, const float* __restrict__ qkt,
                                              const float* __restrict__ alpha, const float* __restrict__ beta,
                                              const float* __restrict__ mu, const float* __restrict__ rsig,
                                              float* __restrict__ A, float* __restrict__ Spart,
                                              float* __restrict__ c1part) {
  int b = blockIdx.y, jt = blockIdx.x, j0 = jt * 128;
  __shared__ __align__(16) float xs[16][132];
  __shared__ __align__(16) float us[16][132];
  __shared__ float sm[64][132];
  __shared__ float rsL[128], muL[128], aL[128], bL[128];
  int t = threadIdx.x, tx = t & 15, ty = t >> 4;
  float acc[8][8] = {};
  const size_t inbase = ((size_t)b * Nn + j0) * Dn;
  const size_t ubase = (size_t)b * HIn * Dn;
  for (int k0 = 0; k0 < Dn; k0 += 16) {
#pragma unroll
    for (int e = 0; e < 8; ++e) {
      int idx = t + e * 256;
      int r = idx >> 4, c = idx & 15;
      xs[c][r] = in[inbase + (size_t)r * Dn + k0 + c];
    }
#pragma unroll
    for (int e = 0; e < 8; ++e) {
      int idx = t + e * 256;
      int r = idx >> 4, c = idx & 15;
      us[c][r] = qkt[ubase + (size_t)r * Dn + k0 + c];
    }
    __syncthreads();
#pragma unroll
    for (int kc = 0; kc < 16; ++kc) {
      float4 x0 = *reinterpret_cast<const float4*>(&xs[kc][ty * 8]);
      float4 x1 = *reinterpret_cast<const float4*>(&xs[kc][ty * 8 + 4]);
      float4 u0 = *reinterpret_cast<const float4*>(&us[kc][tx * 8]);
      float4 u1 = *reinterpret_cast<const float4*>(&us[kc][tx * 8 + 4]);
      float xv[8] = {x0.x, x0.y, x0.z, x0.w, x1.x, x1.y, x1.z, x1.w};
      float uv[8] = {u0.x, u0.y, u0.z, u0.w, u1.x, u1.y, u1.z, u1.w};
#pragma unroll
      for (int a_ = 0; a_ < 8; ++a_)
#pragma unroll
        for (int b_ = 0; b_ < 8; ++b_) acc[a_][b_] += xv[a_] * uv[b_];
    }
    __syncthreads();
  }
  if (t < 128) {
    rsL[t] = rsig[(size_t)b * Nn + j0 + t];
    muL[t] = mu[(size_t)b * Nn + j0 + t];
    aL[t] = alpha[b * HIn + t];
    bL[t] = beta[b * HIn + t];
  }
  for (int half = 0; half < 2; ++half) {
    __syncthreads();
    if ((ty >> 3) == half) {
#pragma unroll
      for (int ji = 0; ji < 8; ++ji) {
        int jl = (ty & 7) * 8 + ji;
        int jg = half * 64 + jl;
        float rs = rsL[jg], mr = muL[jg] * rs;
#pragma unroll
        for (int ui = 0; ui < 8; ++ui) {
          int hi = tx * 8 + ui;
          sm[jl][hi] = acc[ji][ui] * rs + aL[hi] - mr * bL[hi];
        }
      }
    }
    __syncthreads();
    for (int task = t; task < 512; task += 256) {
      int j = task & 63, h = task >> 6;
      float* p = &sm[j][h * 16];
      float mx = p[0];
#pragma unroll
      for (int i = 1; i < 16; ++i) mx = fmaxf(mx, p[i]);
      float e[16];
      float ssum = 0.0f;
#pragma unroll
      for (int i = 0; i < 16; ++i) { e[i] = expf(p[i] - mx); ssum += e[i]; }
      float inv = 1.0f / ssum;
#pragma unroll
      for (int i = 0; i < 16; ++i) p[i] = e[i] * inv + kEps;
    }
    __syncthreads();
    if (t < 128) {
      float ss = 0.0f, cc = 0.0f;
#pragma unroll
      for (int j = 0; j < 64; ++j) {
        float a = sm[j][t];
        ss += a;
        cc += a * muL[half * 64 + j] * rsL[half * 64 + j];
      }
      int sub = (b * 64 + jt * 2 + half) * HIn + t;
      Spart[sub] = ss;
      c1part[sub] = cc;
    }
    for (int idx = t; idx < 8192; idx += 256) {
      int hi = idx >> 6, j = idx & 63;
      A[(size_t)(b * HIn + hi) * Nn + j0 + half * 64 + j] = sm[j][hi] * rsL[half * 64 + j];
    }
  }
}

// ---------------- reduce partial S / c1 ----------------
__global__ void k_reduceS(const float* __restrict__ Spart, const float* __restrict__ c1part,
                          float* __restrict__ S, float* __restrict__ c1) {
  int g = blockIdx.x * 256 + threadIdx.x;
  if (g >= Bn * HIn) return;
  int b = g >> 7, hi = g & 127;
  float s = 0.0f, c = 0.0f;
  for (int tj = 0; tj < 64; ++tj) {
    s += Spart[(b * 64 + tj) * HIn + hi];
    c += c1part[(b * 64 + tj) * HIn + hi];
  }
  S[g] = s;
  c1[g] = c;
}

// ---------------- AX = A @ X  (K-split x4) ----------------
__global__ __launch_bounds__(256) void k_ax(const float* __restrict__ Abuf, const float* __restrict__ in,
                                            float* __restrict__ AXp) {
  int d0 = blockIdx.x * 128;
  int kp = blockIdx.y;
  int b = blockIdx.z;
  __shared__ __align__(16) float as_[16][132];
  __shared__ __align__(16) float xs_[16][132];
  int t = threadIdx.x, tx = t & 15, ty = t >> 4;
  float acc[8][8] = {};
  for (int k0 = kp * 1024; k0 < kp * 1024 + 1024; k0 += 16) {
#pragma unroll
    for (int e = 0; e < 8; ++e) {
      int idx = t + e * 256;
      int r = idx >> 4, c = idx & 15;
      as_[c][r] = Abuf[(size_t)(b * HIn + r) * Nn + k0 + c];
    }
#pragma unroll
    for (int e = 0; e < 8; ++e) {
      int idx = t + e * 256;
      int kc = idx >> 7, dd = idx & 127;
      xs_[kc][dd] = in[((size_t)b * Nn + k0 + kc) * Dn + d0 + dd];
    }
    __syncthreads();
#pragma unroll
    for (int kc = 0; kc < 16; ++kc) {
      float4 a0 = *reinterpret_cast<const float4*>(&as_[kc][ty * 8]);
      float4 a1 = *reinterpret_cast<const float4*>(&as_[kc][ty * 8 + 4]);
      float4 x0 = *reinterpret_cast<const float4*>(&xs_[kc][tx * 8]);
      float4 x1 = *reinterpret_cast<const float4*>(&xs_[kc][tx * 8 + 4]);
      float av[8] = {a0.x, a0.y, a0.z, a0.w, a1.x, a1.y, a1.z, a1.w};
      float xv[8] = {x0.x, x0.y, x0.z, x0.w, x1.x, x1.y, x1.z, x1.w};
#pragma unroll
      for (int u = 0; u < 8; ++u)
#pragma unroll
        for (int v = 0; v < 8; ++v) acc[u][v] += av[u] * xv[v];
    }
    __syncthreads();
  }
#pragma unroll
  for (int u = 0; u < 8; ++u)
#pragma unroll
    for (int v = 0; v < 8; ++v)
      AXp[(((size_t)kp * Bn + b) * HIn + ty * 8 + u) * Dn + d0 + tx * 8 + v] = acc[u][v];
}

// ---------------- upd = ((w*(G-c1)/S + b) @ Wv_h) + bv ----------------
__global__ __launch_bounds__(256) void k_upd(const float* __restrict__ AXp, const float* __restrict__ S,
                                             const float* __restrict__ c1, const float* __restrict__ lnw,
                                             const float* __restrict__ lnb, const float* __restrict__ Wv,
                                             const float* __restrict__ bv, float* __restrict__ upd) {
  int b = blockIdx.y, hi = blockIdx.x, h = hi >> 4, i = hi & 15;
  __shared__ float vx[512];
  __shared__ float red[256];
  int t = threadIdx.x;
  float Sv = S[b * HIn + hi], c1v = c1[b * HIn + hi];
  float invS = 1.0f / Sv;
  for (int d = t; d < Dn; d += 256) {
    float G = 0.0f;
#pragma unroll
    for (int kp = 0; kp < 4; ++kp) G += AXp[(((size_t)kp * Bn + b) * HIn + hi) * Dn + d];
    vx[d] = lnw[d] * (G - c1v) * invS + lnb[d];
  }
  __syncthreads();
  int cc = t & 63, qd = t >> 6;
  float p = 0.0f;
  for (int d = qd * 128; d < qd * 128 + 128; ++d) p += vx[d] * Wv[(size_t)d * Dn + h * 64 + cc];
  red[t] = p;
  __syncthreads();
  if (qd == 0) {
    float v = red[cc] + red[64 + cc] + red[128 + cc] + red[192 + cc] + bv[h * 64 + cc];
    upd[(size_t)(b * NSn + i) * Dn + h * 64 + cc] = v;
  }
}

// ---------------- GRU (in-place slots) ----------------
__global__ __launch_bounds__(256) void k_gru(const float* __restrict__ gi, const float* __restrict__ gh,
                                             float* __restrict__ slots) {
  int r = blockIdx.x;
  for (int c = threadIdx.x; c < Dn; c += 256) {
    float xr = gi[(size_t)r * 1536 + c] + gh[(size_t)r * 1536 + c];
    float xz = gi[(size_t)r * 1536 + 512 + c] + gh[(size_t)r * 1536 + 512 + c];
    float xin = gi[(size_t)r * 1536 + 1024 + c];
    float xhn = gh[(size_t)r * 1536 + 1024 + c];
    float rg = 1.0f / (1.0f + expf(-xr));
    float zg = 1.0f / (1.0f + expf(-xz));
    float ng = tanhf(xin + rg * xhn);
    float sp = slots[(size_t)r * Dn + c];
    slots[(size_t)r * Dn + c] = (1.0f - zg) * ng + zg * sp;
  }
}

// ---------------- keep gate (zero dropped slots in place) ----------------
__global__ void k_keepscale(const float* __restrict__ Wkeep, const float* __restrict__ gk,
                            float* __restrict__ slots) {
  int g = blockIdx.x;
  int lane = threadIdx.x;
  float4* sp = reinterpret_cast<float4*>(slots + (size_t)g * Dn) + lane * 2;
  float4 s0 = sp[0], s1 = sp[1];
  float sv[8] = {s0.x, s0.y, s0.z, s0.w, s1.x, s1.y, s1.z, s1.w};
  double d0 = 0.0, d1 = 0.0;
#pragma unroll
  for (int e = 0; e < 8; ++e) {
    int d = lane * 8 + e;
    d0 += (double)sv[e] * (double)Wkeep[d * 2];
    d1 += (double)sv[e] * (double)Wkeep[d * 2 + 1];
  }
  d0 = wredd(d0);
  d1 = wredd(d1);
  int keepi = 0;
  if (lane == 0) keepi = ((d1 + (double)gk[g * 2 + 1]) > (d0 + (double)gk[g * 2])) ? 1 : 0;
  keepi = __shfl(keepi, 0);
  if (!keepi) {
    float4 z = {0.0f, 0.0f, 0.0f, 0.0f};
    sp[0] = z;
    sp[1] = z;
  }
}

// ---------------- per-slot scalars for route decomposition ----------------
__global__ void k_slotscalars(const float* __restrict__ slots, const float* __restrict__ lnw,
                              const float* __restrict__ lnb, double* __restrict__ swd,
                              double* __restrict__ sbd) {
  int g = blockIdx.x, lane = threadIdx.x;
  const float4* sp = reinterpret_cast<const float4*>(slots + (size_t)g * Dn) + lane * 2;
  const float4* wp = reinterpret_cast<const float4*>(lnw) + lane * 2;
  const float4* bp = reinterpret_cast<const float4*>(lnb) + lane * 2;
  float4 s0 = sp[0], s1 = sp[1], w0 = wp[0], w1 = wp[1], b0 = bp[0], b1 = bp[1];
  double pw = (double)s0.x * w0.x + (double)s0.y * w0.y + (double)s0.z * w0.z + (double)s0.w * w0.w +
              (double)s1.x * w1.x + (double)s1.y * w1.y + (double)s1.z * w1.z + (double)s1.w * w1.w;
  double pb = (double)s0.x * b0.x + (double)s0.y * b0.y + (double)s0.z * b0.z + (double)s0.w * b0.w +
              (double)s1.x * b1.x + (double)s1.y * b1.y + (double)s1.z * b1.z + (double)s1.w * b1.w;
  pw = wredd(pw);
  pb = wredd(pb);
  if (lane == 0) { swd[g] = pw; sbd[g] = pb; }
}

// ---------------- hard route + gather output (tiled mini-GEMM) ----------------
// Block: 128 tokens x 16 slots, K=512. f32 accumulate in 128-K chunks, f64 combine.
__global__ __launch_bounds__(256) void k_route_out(const float* __restrict__ in, const float* __restrict__ slots,
                                                   const float* __restrict__ lnw, const double* __restrict__ swd,
                                                   const double* __restrict__ sbd, const float* __restrict__ mu,
                                                   const float* __restrict__ rsig,
                                                   const float* __restrict__ g_route, float* __restrict__ out) {
  int b = blockIdx.y, j0 = blockIdx.x * 128;
  __shared__ __align__(16) float sl[16 * 516];   // raw slots, padded stride
  __shared__ __align__(16) float lw[512];
  __shared__ __align__(16) float xs[16][132];    // x*lnw, transposed [k][j]
  __shared__ double lgd[128][17];
  __shared__ int besti[128];
  int t = threadIdx.x, tx = t & 15, ty = t >> 4;

  // stage slots + ln_in_w
  for (int idx = t; idx < 2048; idx += 256) {
    int i = idx >> 7, c = idx & 127;
    *reinterpret_cast<float4*>(&sl[i * 516 + c * 4]) =
        *reinterpret_cast<const float4*>(&slots[(size_t)(b * NSn + i) * Dn + c * 4]);
  }
  if (t < 128)
    *reinterpret_cast<float4*>(&lw[t * 4]) = *reinterpret_cast<const float4*>(&lnw[t * 4]);

  float acc[8] = {};
  double accd[8] = {};
  const size_t inbase = ((size_t)b * Nn + j0) * Dn;
  __syncthreads();

  for (int k0 = 0; k0 < Dn; k0 += 16) {
    float pre[8];
#pragma unroll
    for (int e = 0; e < 8; ++e) {
      int idx = t + e * 256;
      int r = idx >> 4, c = idx & 15;
      pre[e] = in[inbase + (size_t)r * Dn + k0 + c];
    }
    __syncthreads();
#pragma unroll
    for (int e = 0; e < 8; ++e) {
      int idx = t + e * 256;
      int r = idx >> 4, c = idx & 15;
      xs[c][r] = pre[e] * lw[k0 + c];
    }
    __syncthreads();
#pragma unroll
    for (int kc = 0; kc < 16; ++kc) {
      float sv = sl[tx * 516 + k0 + kc];
      float4 x0 = *reinterpret_cast<const float4*>(&xs[kc][ty * 8]);
      float4 x1 = *reinterpret_cast<const float4*>(&xs[kc][ty * 8 + 4]);
      acc[0] += x0.x * sv; acc[1] += x0.y * sv; acc[2] += x0.z * sv; acc[3] += x0.w * sv;
      acc[4] += x1.x * sv; acc[5] += x1.y * sv; acc[6] += x1.z * sv; acc[7] += x1.w * sv;
    }
    if ((k0 & 127) == 112) {  // end of each 128-K chunk
#pragma unroll
      for (int e = 0; e < 8; ++e) { accd[e] += (double)acc[e]; acc[e] = 0.0f; }
    }
  }

  // logits in f64 (identical formula to the verified version)
  double sw_i = swd[b * NSn + tx], sb_i = sbd[b * NSn + tx];
#pragma unroll
  for (int r = 0; r < 8; ++r) {
    int j = ty * 8 + r;
    double rsj = (double)rsig[(size_t)b * Nn + j0 + j];
    double muj = (double)mu[(size_t)b * Nn + j0 + j];
    double g = (double)g_route[((size_t)b * NSn + tx) * Nn + j0 + j];
    lgd[j][tx] = (double)kScale * (rsj * accd[r] + sb_i - muj * rsj * sw_i) + g;
  }
  __syncthreads();
  if (t < 128) {
    double best = lgd[t][0];
    int bi = 0;
#pragma unroll
    for (int i = 1; i < 16; ++i) {
      double v = lgd[t][i];
      if (v > best) { best = v; bi = i; }
    }
    besti[t] = bi;
  }
  __syncthreads();
  // cooperative gather of winning slot rows
  for (int idx = t; idx < 128 * 128; idx += 256) {
    int j = idx >> 7, c = idx & 127;
    *reinterpret_cast<float4*>(&out[inbase + (size_t)j * Dn + c * 4]) =
        *reinterpret_cast<const float4*>(&sl[besti[j] * 516 + c * 4]);
  }
}

extern "C" void kernel_launch(void* const* d_in, const int* in_sizes, int n_in,
                              void* d_out, int out_size, void* d_ws, size_t ws_size,
                              hipStream_t stream) {
  (void)in_sizes; (void)n_in; (void)out_size; (void)ws_size;
  const float* in = (const float*)d_in[0];
  const float* slots_mu = (const float*)d_in[1];
  const float* slots_ls = (const float*)d_in[2];
  const float* ln_in_w = (const float*)d_in[3];
  const float* ln_in_b = (const float*)d_in[4];
  const float* ln_s_w = (const float*)d_in[5];
  const float* ln_s_b = (const float*)d_in[6];
  const float* ln_ff_w = (const float*)d_in[7];
  const float* ln_ff_b = (const float*)d_in[8];
  const float* Wq = (const float*)d_in[9];
  const float* bq = (const float*)d_in[10];
  const float* Wk = (const float*)d_in[11];
  const float* bk = (const float*)d_in[12];
  const float* Wv = (const float*)d_in[13];
  const float* bv = (const float*)d_in[14];
  const float* Wc = (const float*)d_in[15];
  const float* bc = (const float*)d_in[16];
  const float* Wih = (const float*)d_in[17];
  const float* bih = (const float*)d_in[18];
  const float* Whh = (const float*)d_in[19];
  const float* bhh = (const float*)d_in[20];
  const float* W1 = (const float*)d_in[21];
  const float* b1 = (const float*)d_in[22];
  const float* W2 = (const float*)d_in[23];
  const float* b2 = (const float*)d_in[24];
  const float* Wkeep = (const float*)d_in[25];
  const float* noise = (const float*)d_in[26];
  const float* g_keep = (const float*)d_in[27];
  const float* g_route = (const float*)d_in[28];
  float* out = (float*)d_out;

  char* wptr = (char*)d_ws;
  auto alloc = [&](size_t bytes) {
    char* p = wptr;
    wptr += (bytes + 255) & ~(size_t)255;
    return p;
  };
  float* mu = (float*)alloc((size_t)Bn * Nn * 4);
  float* rsig = (float*)alloc((size_t)Bn * Nn * 4);
  float* slots = (float*)alloc((size_t)Bn * NSn * Dn * 4);
  float* sln = (float*)alloc((size_t)Bn * NSn * Dn * 4);
  float* qbuf = (float*)alloc((size_t)Bn * NSn * Dn * 4);
  float* qkt = (float*)alloc((size_t)Bn * HIn * Dn * 4);
  float* alpha = (float*)alloc((size_t)Bn * HIn * 4);
  float* beta = (float*)alloc((size_t)Bn * HIn * 4);
  float* Abuf = (float*)alloc((size_t)Bn * HIn * Nn * 4);
  float* Spart = (float*)alloc((size_t)Bn * 64 * HIn * 4);
  float* c1part = (float*)alloc((size_t)Bn * 64 * HIn * 4);
  float* Sfull = (float*)alloc((size_t)Bn * HIn * 4);
  float* c1full = (float*)alloc((size_t)Bn * HIn * 4);
  float* AXp = (float*)alloc((size_t)4 * Bn * HIn * Dn * 4);
  float* updb = (float*)alloc((size_t)Bn * NSn * Dn * 4);
  float* updc = (float*)alloc((size_t)Bn * NSn * Dn * 4);
  float* gibuf = (float*)alloc((size_t)Bn * NSn * 1536 * 4);
  float* ghbuf = (float*)alloc((size_t)Bn * NSn * 1536 * 4);
  float* hbuf = (float*)alloc((size_t)Bn * NSn * 2048 * 4);
  double* swd = (double*)alloc((size_t)Bn * NSn * 8);
  double* sbd = (double*)alloc((size_t)Bn * NSn * 8);

  k_rowstats<<<Bn * Nn / 4, 256, 0, stream>>>(in, mu, rsig);
  k_slots_init<<<Bn * NSn, 256, 0, stream>>>(slots_mu, slots_ls, noise, slots);

  for (int it = 0; it < 3; ++it) {
    k_ln_rows<<<Bn * NSn, 256, 0, stream>>>(slots, ln_s_w, ln_s_b, sln);
    k_gemm_sm<false, false, false><<<dim3(8, 8), 256, 0, stream>>>(sln, Wq, bq, qbuf, 512, 512);
    k_qkt<<<dim3(HIn, Bn), 256, 0, stream>>>(qbuf, Wk, bk, ln_in_w, ln_in_b, qkt, alpha, beta);
    k_dots<<<dim3(Nn / 128, Bn), 256, 0, stream>>>(in, qkt, alpha, beta, mu, rsig, Abuf, Spart, c1part);
    k_reduceS<<<(Bn * HIn + 255) / 256, 256, 0, stream>>>(Spart, c1part, Sfull, c1full);
    k_ax<<<dim3(4, 4, Bn), 256, 0, stream>>>(Abuf, in, AXp);
    k_upd<<<dim3(HIn, Bn), 256, 0, stream>>>(AXp, Sfull, c1full, ln_in_w, ln_in_b, Wv, bv, updb);
    k_gemm_sm<false, false, false><<<dim3(8, 8), 256, 0, stream>>>(updb, Wc, bc, updc, 512, 512);
    k_gemm_sm<true, false, false><<<dim3(24, 8), 256, 0, stream>>>(updc, Wih, bih, gibuf, 1536, 512);
    k_gemm_sm<true, false, false><<<dim3(24, 8), 256, 0, stream>>>(slots, Whh, bhh, ghbuf, 1536, 512);
    k_gru<<<Bn * NSn, 256, 0, stream>>>(gibuf, ghbuf, slots);
    k_ln_rows<<<Bn * NSn, 256, 0, stream>>>(slots, ln_ff_w, ln_ff_b, sln);
    k_gemm_sm<false, true, false><<<dim3(32, 8), 256, 0, stream>>>(sln, W1, b1, hbuf, 2048, 512);
    k_gemm_sm<false, false, true><<<dim3(8, 8), 256, 0, stream>>>(hbuf, W2, b2, slots, 512, 2048);
  }

  k_keepscale<<<Bn * NSn, 64, 0, stream>>>(Wkeep, g_keep, slots);
  k_slotscalars<<<Bn * NSn, 64, 0, stream>>>(slots, ln_in_w, ln_in_b, swd, sbd);
  k_route_out<<<dim3(Nn / 128, Bn), 256, 0, stream>>>(in, slots, ln_in_w, swd, sbd, mu, rsig, g_route, out);
}